// Round 9
// baseline (551.625 us; speedup 1.0000x reference)
//
#include <hip/hip_runtime.h>

// Sparse submanifold 3x3x3 conv (64->64) + BatchNorm(batch stats) + LeakyReLU(0.01)
// Rulebook strategy, occupancy bitmask, contention-free counters.
//   K1 memset cnt/stats (20KB) + occ bitmask (1.2MB)
//   K2 scatter: grid[lin]=i, atomicOr occ bit
//   K3 rulebook (block-aggregated LDS staging, padded global reservation)
//   K4 center GEMM: feat tile staged in LDS (coalesced, stride-68 pad), thread =
//      4 rows x 8 ch register block; W reads amortized 4x; conflict-free banks
//   K5 per-offset gather-GEMM: lane=channel, W-COLUMN IN REGISTERS (no LDS),
//      4 pairs/iter for ILP, coalesced 256B atomics
//   K6 channel sum/sumsq reduction (padded atomics)
//   K7 normalize + leaky relu (in place on out)

#define DD 96
#define HH 320
#define WW 320
#define GRID_ELEMS (DD * HH * WW)
#define OCC_WORDS (GRID_ELEMS / 32)   // 1.2 MB; WW%32==0 => rows word-aligned
#define CIN 64
#define COUT 64
#define PAIR_CAP 16384
#define STAGE_CAP 40    // per-(block,k) staging; mean 3.9 hits, P(>40) ~ 0
#define TILE_R 128      // center_k rows per block
#define FSTRIDE 68      // LDS feat row stride (dwords): bank = 4g mod 32 -> conflict-free
#define EPSV 1e-5f
#define SLOPE 0.01f

__global__ void scatter_k(const int* __restrict__ coords, int* __restrict__ grid,
                          unsigned* __restrict__ occ, int N) {
    int i = blockIdx.x * 256 + threadIdx.x;
    if (i >= N) return;
    int z = coords[3 * i], y = coords[3 * i + 1], x = coords[3 * i + 2];
    int l = (z * HH + y) * WW + x;
    grid[l] = i;
    atomicOr(&occ[l >> 5], 1u << (l & 31));
}

// Per-voxel probe of L2-resident bitmask; hits staged in LDS; one padded global
// atomic per (block,k) reserves the compact range; bulk copy-out.
__global__ void rulebook_k(const int* __restrict__ coords, const int* __restrict__ grid,
                           const unsigned* __restrict__ occ,
                           int* __restrict__ cnt, int2* __restrict__ pairs, int N) {
    __shared__ int scnt[27];
    __shared__ int sbase[27];
    __shared__ int2 stage[27][STAGE_CAP];
    int tid = threadIdx.x;
    if (tid < 27) scnt[tid] = 0;
    __syncthreads();

    int i = blockIdx.x * 256 + tid;
    if (i < N) {
        int z = coords[3 * i], y = coords[3 * i + 1], x = coords[3 * i + 2];
        int lo = x > 0 ? x - 1 : 0;
        int hi = x < WW - 1 ? x + 1 : WW - 1;
        int wlo = lo >> 5, whi = hi >> 5;

        unsigned wa[9], wb9[9];
        int rwb[9];
#pragma unroll
        for (int r = 0; r < 9; ++r) {
            int zz = z + r / 3 - 1;
            int yy = y + r % 3 - 1;
            bool ok = ((unsigned)zz < DD) && ((unsigned)yy < HH);
            int base = (zz * HH + yy) * WW;      // word-aligned (WW % 32 == 0)
            rwb[r] = base;
            int wbase = base >> 5;
            wa[r]  = ok ? occ[wbase + wlo] : 0u;
            wb9[r] = ok ? occ[wbase + whi] : 0u;
        }
#pragma unroll
        for (int r = 0; r < 9; ++r) {
            for (int xx = lo; xx <= hi; ++xx) {
                if (r == 4 && xx == x) continue;          // center handled by center_k
                unsigned w = ((xx >> 5) == wlo) ? wa[r] : wb9[r];
                if ((w >> (xx & 31)) & 1u) {
                    int j = grid[rwb[r] + xx];
                    int k = r * 3 + (xx - x + 1);         // 0..26, never 13
                    int pos = atomicAdd(&scnt[k], 1);     // LDS atomic: cheap
                    if (pos < STAGE_CAP) stage[k][pos] = make_int2(i, j);
                }
            }
        }
    }
    __syncthreads();
    if (tid < 27) {
        int c = scnt[tid];
        if (c > STAGE_CAP) c = STAGE_CAP;
        scnt[tid] = c;
        if (c > 0) sbase[tid] = atomicAdd(&cnt[tid * 32], c);  // 128B-padded counters
    }
    __syncthreads();
    for (int s = tid; s < 27 * STAGE_CAP; s += 256) {
        int k = s / STAGE_CAP, p = s % STAGE_CAP;
        if (p < scnt[k]) {
            int pos = sbase[k] + p;
            if (pos < PAIR_CAP) pairs[k * PAIR_CAP + pos] = stage[k][p];
        }
    }
}

// Dense GEMM, 128-row tile in LDS. Thread = 4 rows (strided by 32) x 8 channels.
// Global reads/writes fully coalesced; LDS reads conflict-free (stride 68);
// W-fragment reads amortized over 4 rows in registers.
__global__ void center_k(const float* __restrict__ feat, const float* __restrict__ w13,
                         float* __restrict__ out, int N) {
    __shared__ float wl[CIN * COUT];          // 16 KB
    __shared__ float fl[TILE_R * FSTRIDE];    // 34.8 KB
    {
        const float4* ws4 = (const float4*)w13;
        float4* wl4 = (float4*)wl;
        for (int t = threadIdx.x; t < CIN * COUT / 4; t += 256) wl4[t] = ws4[t];
    }
    int base_row = blockIdx.x * TILE_R;
    for (int t = threadIdx.x; t < TILE_R * 16; t += 256) {
        int r = t >> 4, c4 = t & 15;
        int gr = base_row + r;
        float4 v = (gr < N) ? ((const float4*)feat)[(size_t)gr * 16 + c4]
                            : make_float4(0.f, 0.f, 0.f, 0.f);
        *(float4*)&fl[r * FSTRIDE + c4 * 4] = v;
    }
    __syncthreads();

    int g = threadIdx.x >> 3;            // 0..31: row within 32-row stripe
    int c0 = (threadIdx.x & 7) * 8;      // 8-channel group
    float4 acc[4][2];
#pragma unroll
    for (int r = 0; r < 4; ++r) {
        acc[r][0] = make_float4(0.f, 0.f, 0.f, 0.f);
        acc[r][1] = make_float4(0.f, 0.f, 0.f, 0.f);
    }
#pragma unroll 4
    for (int ci4 = 0; ci4 < 16; ++ci4) {
        float4 f[4];
#pragma unroll
        for (int r = 0; r < 4; ++r)
            f[r] = *(const float4*)&fl[(g + 32 * r) * FSTRIDE + ci4 * 4];
#pragma unroll
        for (int u = 0; u < 4; ++u) {
            float4 wa = *(const float4*)&wl[(ci4 * 4 + u) * COUT + c0];
            float4 wb = *(const float4*)&wl[(ci4 * 4 + u) * COUT + c0 + 4];
#pragma unroll
            for (int r = 0; r < 4; ++r) {
                float fv = (&f[r].x)[u];
                acc[r][0].x += fv * wa.x;
                acc[r][0].y += fv * wa.y;
                acc[r][0].z += fv * wa.z;
                acc[r][0].w += fv * wa.w;
                acc[r][1].x += fv * wb.x;
                acc[r][1].y += fv * wb.y;
                acc[r][1].z += fv * wb.z;
                acc[r][1].w += fv * wb.w;
            }
        }
    }
    float4* o4 = (float4*)out;
#pragma unroll
    for (int r = 0; r < 4; ++r) {
        int row = base_row + g + 32 * r;
        if (row < N) {
            size_t base = (size_t)row * 16 + (c0 >> 2);
            o4[base] = acc[r][0];
            o4[base + 1] = acc[r][1];
        }
    }
}

// Lane = output channel; W[k] column held in 64 REGISTERS (no LDS). 4 pairs per
// iteration: 4 independent accumulators + 64 outstanding broadcast feat loads.
// atomicAdd per pair is ONE contiguous 256B region (4 lines).
__global__ void offset_k(const float* __restrict__ feat, const float* __restrict__ weight,
                         const int2* __restrict__ pairs, const int* __restrict__ cnt,
                         float* __restrict__ out) {
    int k = blockIdx.y;
    if (k >= 13) ++k;  // skip center
    int ck = cnt[k * 32];
    if (ck > PAIR_CAP) ck = PAIR_CAP;
    if ((int)blockIdx.x * 16 >= ck) return;   // uniform early-out
    int lane = threadIdx.x & 63;
    int wave = threadIdx.x >> 6;
    const float* wk = weight + (size_t)k * CIN * COUT;
    float wcol[CIN];
#pragma unroll
    for (int ci = 0; ci < CIN; ++ci) wcol[ci] = wk[ci * COUT + lane];  // coalesced

    for (int p0 = (int)blockIdx.x * 16 + wave * 4; p0 < ck; p0 += (int)gridDim.x * 16) {
        int np = ck - p0;
        int2 pr[4];
        const float4* fr[4];
#pragma unroll
        for (int q = 0; q < 4; ++q) {
            int p = p0 + q < ck ? p0 + q : ck - 1;    // clamp; dead lanes unstored
            pr[q] = pairs[k * PAIR_CAP + p];
            fr[q] = (const float4*)(feat + (size_t)pr[q].y * CIN);
        }
        float acc[4] = {0.f, 0.f, 0.f, 0.f};
#pragma unroll
        for (int ci4 = 0; ci4 < 16; ++ci4) {
            float4 f[4];
#pragma unroll
            for (int q = 0; q < 4; ++q) f[q] = fr[q][ci4];   // wave-uniform broadcast
#pragma unroll
            for (int u = 0; u < 4; ++u) {
                float w = wcol[ci4 * 4 + u];
#pragma unroll
                for (int q = 0; q < 4; ++q) acc[q] += (&f[q].x)[u] * w;
            }
        }
#pragma unroll
        for (int q = 0; q < 4; ++q)
            if (q < np) atomicAdd(&out[(size_t)pr[q].x * COUT + lane], acc[q]);
    }
}

// Padded stats: stats[c*32] = sum_c, stats[(64+c)*32] = sumsq_c (128B per counter)
__global__ void stats_k(const float* __restrict__ out, float* __restrict__ stats, int N) {
    __shared__ float ssum[4][64];
    __shared__ float ssq[4][64];
    int c = threadIdx.x & 63, g = threadIdx.x >> 6;
    float s = 0.f, q = 0.f;
    for (int r = blockIdx.x * 4 + g; r < N; r += gridDim.x * 4) {
        float v = out[(size_t)r * 64 + c];
        s += v;
        q += v * v;
    }
    ssum[g][c] = s;
    ssq[g][c] = q;
    __syncthreads();
    if (threadIdx.x < 64) {
        float ts = ssum[0][c] + ssum[1][c] + ssum[2][c] + ssum[3][c];
        float tq = ssq[0][c] + ssq[1][c] + ssq[2][c] + ssq[3][c];
        atomicAdd(&stats[c * 32], ts);
        atomicAdd(&stats[(64 + c) * 32], tq);
    }
}

__global__ void norm_k(float* __restrict__ out, const float* __restrict__ stats,
                       const float* __restrict__ gamma, const float* __restrict__ beta, int N) {
    int idx = (int)blockIdx.x * 256 + threadIdx.x;
    int total = N * (COUT / 4);
    if (idx >= total) return;
    int c0 = (idx & 15) * 4;
    float inv = 1.0f / (float)N;
    float4 v = ((const float4*)out)[idx];
    float4 r;
#pragma unroll
    for (int u = 0; u < 4; ++u) {
        int c = c0 + u;
        float mean = stats[c * 32] * inv;
        float var = stats[(64 + c) * 32] * inv - mean * mean;
        if (var < 0.f) var = 0.f;
        float sc = gamma[c] * rsqrtf(var + EPSV);
        float sh = beta[c] - mean * sc;
        float y = (&v.x)[u] * sc + sh;
        (&r.x)[u] = (y >= 0.f) ? y : SLOPE * y;
    }
    ((float4*)out)[idx] = r;
}

extern "C" void kernel_launch(void* const* d_in, const int* in_sizes, int n_in,
                              void* d_out, int out_size, void* d_ws, size_t ws_size,
                              hipStream_t stream) {
    const float* feat   = (const float*)d_in[0];
    const int*   coords = (const int*)d_in[1];
    const float* weight = (const float*)d_in[2];
    const float* gamma  = (const float*)d_in[3];
    const float* beta   = (const float*)d_in[4];
    float* out = (float*)d_out;
    int N = in_sizes[0] / CIN;

    // workspace layout (~44.1 MB of the 256 MiB ws)
    char* ws = (char*)d_ws;
    int* grid = (int*)ws;                                   // 39.32 MB (gated by occ, no memset)
    size_t off = (size_t)GRID_ELEMS * 4;
    int* cnt = (int*)(ws + off);                            // 27*32 ints padded -> 4KB slot
    float* stats = (float*)(ws + off + 4096);               // 128*32 floats padded = 16KB
    int2* pairs = (int2*)(ws + off + 4096 + 16384);         // 27*PAIR_CAP*8 = 3.54 MB
    size_t occ_off = off + 4096 + 16384 + (size_t)27 * PAIR_CAP * 8;
    unsigned* occ = (unsigned*)(ws + occ_off);              // 1.2 MB bitmask

    hipMemsetAsync(ws + off, 0, 4096 + 16384, stream);      // counters + stats
    hipMemsetAsync(occ, 0, (size_t)OCC_WORDS * 4, stream);  // bitmask = 0

    int nb = (N + 255) / 256;
    scatter_k<<<nb, 256, 0, stream>>>(coords, grid, occ, N);
    rulebook_k<<<nb, 256, 0, stream>>>(coords, grid, occ, cnt, pairs, N);
    int nbc = (N + TILE_R - 1) / TILE_R;
    center_k<<<nbc, 256, 0, stream>>>(feat, weight + 13 * CIN * COUT, out, N);
    offset_k<<<dim3(48, 26), 256, 0, stream>>>(feat, weight, pairs, cnt, out);
    stats_k<<<256, 256, 0, stream>>>(out, stats, N);
    int nb4 = (N * (COUT / 4) + 255) / 256;
    norm_k<<<nb4, 256, 0, stream>>>(out, stats, gamma, beta, N);
}

// Round 10
// 540.301 us; speedup vs baseline: 1.0210x; 1.0210x over previous
//
#include <hip/hip_runtime.h>

// Sparse submanifold 3x3x3 conv (64->64) + BatchNorm(batch stats) + LeakyReLU(0.01)
// Rulebook strategy, occupancy bitmask, contention-free counters.
//   K1 memset cnt/stats (20KB) + occ bitmask (1.2MB)
//   K2 scatter: grid[lin]=i, atomicOr occ bit
//   K3 rulebook (block-aggregated LDS staging, padded global reservation)
//   K4 center GEMM: feat tile staged in LDS (coalesced, stride-68 pad), thread =
//      4 rows x 8 ch register block; W reads amortized 4x; conflict-free banks
//   K5 per-offset gather-GEMM: lane=channel, W in LDS (scalar broadcast-free
//      column reads), WAVE-PER-4-PAIRS for ILP, coalesced 256B atomics.
//      NOTE (R9 lesson): W-column in per-lane registers (float wcol[64]) gets
//      demoted to scratch (VGPR=64, FETCH 381MB) -> never do that.
//   K6 channel sum/sumsq reduction (padded atomics)
//   K7 normalize + leaky relu (in place on out)

#define DD 96
#define HH 320
#define WW 320
#define GRID_ELEMS (DD * HH * WW)
#define OCC_WORDS (GRID_ELEMS / 32)   // 1.2 MB; WW%32==0 => rows word-aligned
#define CIN 64
#define COUT 64
#define PAIR_CAP 16384
#define STAGE_CAP 40    // per-(block,k) staging; mean 3.9 hits, P(>40) ~ 0
#define TILE_R 128      // center_k rows per block
#define FSTRIDE 68      // LDS feat row stride (dwords): bank = 4g mod 32 -> conflict-free
#define EPSV 1e-5f
#define SLOPE 0.01f

__global__ void scatter_k(const int* __restrict__ coords, int* __restrict__ grid,
                          unsigned* __restrict__ occ, int N) {
    int i = blockIdx.x * 256 + threadIdx.x;
    if (i >= N) return;
    int z = coords[3 * i], y = coords[3 * i + 1], x = coords[3 * i + 2];
    int l = (z * HH + y) * WW + x;
    grid[l] = i;
    atomicOr(&occ[l >> 5], 1u << (l & 31));
}

// Per-voxel probe of L2-resident bitmask; hits staged in LDS; one padded global
// atomic per (block,k) reserves the compact range; bulk copy-out.
__global__ void rulebook_k(const int* __restrict__ coords, const int* __restrict__ grid,
                           const unsigned* __restrict__ occ,
                           int* __restrict__ cnt, int2* __restrict__ pairs, int N) {
    __shared__ int scnt[27];
    __shared__ int sbase[27];
    __shared__ int2 stage[27][STAGE_CAP];
    int tid = threadIdx.x;
    if (tid < 27) scnt[tid] = 0;
    __syncthreads();

    int i = blockIdx.x * 256 + tid;
    if (i < N) {
        int z = coords[3 * i], y = coords[3 * i + 1], x = coords[3 * i + 2];
        int lo = x > 0 ? x - 1 : 0;
        int hi = x < WW - 1 ? x + 1 : WW - 1;
        int wlo = lo >> 5, whi = hi >> 5;

        unsigned wa[9], wb9[9];
        int rwb[9];
#pragma unroll
        for (int r = 0; r < 9; ++r) {
            int zz = z + r / 3 - 1;
            int yy = y + r % 3 - 1;
            bool ok = ((unsigned)zz < DD) && ((unsigned)yy < HH);
            int base = (zz * HH + yy) * WW;      // word-aligned (WW % 32 == 0)
            rwb[r] = base;
            int wbase = base >> 5;
            wa[r]  = ok ? occ[wbase + wlo] : 0u;
            wb9[r] = ok ? occ[wbase + whi] : 0u;
        }
#pragma unroll
        for (int r = 0; r < 9; ++r) {
            for (int xx = lo; xx <= hi; ++xx) {
                if (r == 4 && xx == x) continue;          // center handled by center_k
                unsigned w = ((xx >> 5) == wlo) ? wa[r] : wb9[r];
                if ((w >> (xx & 31)) & 1u) {
                    int j = grid[rwb[r] + xx];
                    int k = r * 3 + (xx - x + 1);         // 0..26, never 13
                    int pos = atomicAdd(&scnt[k], 1);     // LDS atomic: cheap
                    if (pos < STAGE_CAP) stage[k][pos] = make_int2(i, j);
                }
            }
        }
    }
    __syncthreads();
    if (tid < 27) {
        int c = scnt[tid];
        if (c > STAGE_CAP) c = STAGE_CAP;
        scnt[tid] = c;
        if (c > 0) sbase[tid] = atomicAdd(&cnt[tid * 32], c);  // 128B-padded counters
    }
    __syncthreads();
    for (int s = tid; s < 27 * STAGE_CAP; s += 256) {
        int k = s / STAGE_CAP, p = s % STAGE_CAP;
        if (p < scnt[k]) {
            int pos = sbase[k] + p;
            if (pos < PAIR_CAP) pairs[k * PAIR_CAP + pos] = stage[k][p];
        }
    }
}

// Dense GEMM, 128-row tile in LDS. Thread = 4 rows (strided by 32) x 8 channels.
// Global reads/writes fully coalesced; LDS reads conflict-free (stride 68);
// W-fragment reads amortized over 4 rows in registers.
__global__ void center_k(const float* __restrict__ feat, const float* __restrict__ w13,
                         float* __restrict__ out, int N) {
    __shared__ float wl[CIN * COUT];          // 16 KB
    __shared__ float fl[TILE_R * FSTRIDE];    // 34.8 KB
    {
        const float4* ws4 = (const float4*)w13;
        float4* wl4 = (float4*)wl;
        for (int t = threadIdx.x; t < CIN * COUT / 4; t += 256) wl4[t] = ws4[t];
    }
    int base_row = blockIdx.x * TILE_R;
    for (int t = threadIdx.x; t < TILE_R * 16; t += 256) {
        int r = t >> 4, c4 = t & 15;
        int gr = base_row + r;
        float4 v = (gr < N) ? ((const float4*)feat)[(size_t)gr * 16 + c4]
                            : make_float4(0.f, 0.f, 0.f, 0.f);
        *(float4*)&fl[r * FSTRIDE + c4 * 4] = v;
    }
    __syncthreads();

    int g = threadIdx.x >> 3;            // 0..31: row within 32-row stripe
    int c0 = (threadIdx.x & 7) * 8;      // 8-channel group
    float4 acc[4][2];
#pragma unroll
    for (int r = 0; r < 4; ++r) {
        acc[r][0] = make_float4(0.f, 0.f, 0.f, 0.f);
        acc[r][1] = make_float4(0.f, 0.f, 0.f, 0.f);
    }
#pragma unroll 4
    for (int ci4 = 0; ci4 < 16; ++ci4) {
        float4 f[4];
#pragma unroll
        for (int r = 0; r < 4; ++r)
            f[r] = *(const float4*)&fl[(g + 32 * r) * FSTRIDE + ci4 * 4];
#pragma unroll
        for (int u = 0; u < 4; ++u) {
            float4 wa = *(const float4*)&wl[(ci4 * 4 + u) * COUT + c0];
            float4 wb = *(const float4*)&wl[(ci4 * 4 + u) * COUT + c0 + 4];
#pragma unroll
            for (int r = 0; r < 4; ++r) {
                float fv = (&f[r].x)[u];
                acc[r][0].x += fv * wa.x;
                acc[r][0].y += fv * wa.y;
                acc[r][0].z += fv * wa.z;
                acc[r][0].w += fv * wa.w;
                acc[r][1].x += fv * wb.x;
                acc[r][1].y += fv * wb.y;
                acc[r][1].z += fv * wb.z;
                acc[r][1].w += fv * wb.w;
            }
        }
    }
    float4* o4 = (float4*)out;
#pragma unroll
    for (int r = 0; r < 4; ++r) {
        int row = base_row + g + 32 * r;
        if (row < N) {
            size_t base = (size_t)row * 16 + (c0 >> 2);
            o4[base] = acc[r][0];
            o4[base + 1] = acc[r][1];
        }
    }
}

// Lane = output channel, W[k] staged in LDS (R8-proven). WAVE-PER-4-PAIRS: each
// wl scalar read feeds 4 accumulators (LDS issue halved vs 2-pair), 4 broadcast
// load chains hide gather latency. atomicAdd per pair = ONE contiguous 256B region.
__global__ void offset_k(const float* __restrict__ feat, const float* __restrict__ weight,
                         const int2* __restrict__ pairs, const int* __restrict__ cnt,
                         float* __restrict__ out) {
    int k = blockIdx.y;
    if (k >= 13) ++k;  // skip center
    int ck = cnt[k * 32];
    if (ck > PAIR_CAP) ck = PAIR_CAP;
    if ((int)blockIdx.x * 16 >= ck) return;   // block-uniform early-out (before any sync)
    __shared__ float wl[CIN * COUT];
    {
        const float4* ws4 = (const float4*)(weight + (size_t)k * CIN * COUT);
        float4* wl4 = (float4*)wl;
        for (int t = threadIdx.x; t < CIN * COUT / 4; t += 256) wl4[t] = ws4[t];
    }
    __syncthreads();
    int wave = threadIdx.x >> 6;   // 0..3
    int lane = threadIdx.x & 63;   // output channel
    for (int p0 = (int)blockIdx.x * 16 + wave * 4; p0 < ck; p0 += (int)gridDim.x * 16) {
        int np = ck - p0;
        int2 pr[4];
        const float4* fr[4];
#pragma unroll
        for (int q = 0; q < 4; ++q) {
            int p = (p0 + q < ck) ? p0 + q : ck - 1;   // clamp; surplus unstored
            pr[q] = pairs[k * PAIR_CAP + p];
            fr[q] = (const float4*)(feat + (size_t)pr[q].y * CIN);
        }
        float acc0 = 0.f, acc1 = 0.f, acc2 = 0.f, acc3 = 0.f;
#pragma unroll
        for (int ci4 = 0; ci4 < 16; ++ci4) {
            float4 f0 = fr[0][ci4];                    // wave-uniform -> broadcast
            float4 f1 = fr[1][ci4];
            float4 f2 = fr[2][ci4];
            float4 f3 = fr[3][ci4];
#pragma unroll
            for (int u = 0; u < 4; ++u) {
                float w = wl[(ci4 * 4 + u) * COUT + lane];
                acc0 += (&f0.x)[u] * w;
                acc1 += (&f1.x)[u] * w;
                acc2 += (&f2.x)[u] * w;
                acc3 += (&f3.x)[u] * w;
            }
        }
        atomicAdd(&out[(size_t)pr[0].x * COUT + lane], acc0);
        if (1 < np) atomicAdd(&out[(size_t)pr[1].x * COUT + lane], acc1);
        if (2 < np) atomicAdd(&out[(size_t)pr[2].x * COUT + lane], acc2);
        if (3 < np) atomicAdd(&out[(size_t)pr[3].x * COUT + lane], acc3);
    }
}

// Padded stats: stats[c*32] = sum_c, stats[(64+c)*32] = sumsq_c (128B per counter)
__global__ void stats_k(const float* __restrict__ out, float* __restrict__ stats, int N) {
    __shared__ float ssum[4][64];
    __shared__ float ssq[4][64];
    int c = threadIdx.x & 63, g = threadIdx.x >> 6;
    float s = 0.f, q = 0.f;
    for (int r = blockIdx.x * 4 + g; r < N; r += gridDim.x * 4) {
        float v = out[(size_t)r * 64 + c];
        s += v;
        q += v * v;
    }
    ssum[g][c] = s;
    ssq[g][c] = q;
    __syncthreads();
    if (threadIdx.x < 64) {
        float ts = ssum[0][c] + ssum[1][c] + ssum[2][c] + ssum[3][c];
        float tq = ssq[0][c] + ssq[1][c] + ssq[2][c] + ssq[3][c];
        atomicAdd(&stats[c * 32], ts);
        atomicAdd(&stats[(64 + c) * 32], tq);
    }
}

__global__ void norm_k(float* __restrict__ out, const float* __restrict__ stats,
                       const float* __restrict__ gamma, const float* __restrict__ beta, int N) {
    int idx = (int)blockIdx.x * 256 + threadIdx.x;
    int total = N * (COUT / 4);
    if (idx >= total) return;
    int c0 = (idx & 15) * 4;
    float inv = 1.0f / (float)N;
    float4 v = ((const float4*)out)[idx];
    float4 r;
#pragma unroll
    for (int u = 0; u < 4; ++u) {
        int c = c0 + u;
        float mean = stats[c * 32] * inv;
        float var = stats[(64 + c) * 32] * inv - mean * mean;
        if (var < 0.f) var = 0.f;
        float sc = gamma[c] * rsqrtf(var + EPSV);
        float sh = beta[c] - mean * sc;
        float y = (&v.x)[u] * sc + sh;
        (&r.x)[u] = (y >= 0.f) ? y : SLOPE * y;
    }
    ((float4*)out)[idx] = r;
}

extern "C" void kernel_launch(void* const* d_in, const int* in_sizes, int n_in,
                              void* d_out, int out_size, void* d_ws, size_t ws_size,
                              hipStream_t stream) {
    const float* feat   = (const float*)d_in[0];
    const int*   coords = (const int*)d_in[1];
    const float* weight = (const float*)d_in[2];
    const float* gamma  = (const float*)d_in[3];
    const float* beta   = (const float*)d_in[4];
    float* out = (float*)d_out;
    int N = in_sizes[0] / CIN;

    // workspace layout (~44.1 MB of the 256 MiB ws)
    char* ws = (char*)d_ws;
    int* grid = (int*)ws;                                   // 39.32 MB (gated by occ, no memset)
    size_t off = (size_t)GRID_ELEMS * 4;
    int* cnt = (int*)(ws + off);                            // 27*32 ints padded -> 4KB slot
    float* stats = (float*)(ws + off + 4096);               // 128*32 floats padded = 16KB
    int2* pairs = (int2*)(ws + off + 4096 + 16384);         // 27*PAIR_CAP*8 = 3.54 MB
    size_t occ_off = off + 4096 + 16384 + (size_t)27 * PAIR_CAP * 8;
    unsigned* occ = (unsigned*)(ws + occ_off);              // 1.2 MB bitmask

    hipMemsetAsync(ws + off, 0, 4096 + 16384, stream);      // counters + stats
    hipMemsetAsync(occ, 0, (size_t)OCC_WORDS * 4, stream);  // bitmask = 0

    int nb = (N + 255) / 256;
    scatter_k<<<nb, 256, 0, stream>>>(coords, grid, occ, N);
    rulebook_k<<<nb, 256, 0, stream>>>(coords, grid, occ, cnt, pairs, N);
    int nbc = (N + TILE_R - 1) / TILE_R;
    center_k<<<nbc, 256, 0, stream>>>(feat, weight + 13 * CIN * COUT, out, N);
    offset_k<<<dim3(96, 26), 256, 0, stream>>>(feat, weight, pairs, cnt, out);
    stats_k<<<256, 256, 0, stream>>>(out, stats, N);
    int nb4 = (N * (COUT / 4) + 255) / 256;
    norm_k<<<nb4, 256, 0, stream>>>(out, stats, gamma, beta, N);
}

// Round 11
// 302.063 us; speedup vs baseline: 1.8262x; 1.7887x over previous
//
#include <hip/hip_runtime.h>

// Sparse submanifold 3x3x3 conv (64->64) + BatchNorm(batch stats) + LeakyReLU(0.01)
// Rulebook strategy, occupancy bitmask, contention-free counters.
//   K1 memset cnt/stats (20KB) + occ bitmask (1.2MB)
//   K2 scatter: grid[lin]=i, atomicOr occ bit
//   K3 rulebook (block-aggregated LDS staging, padded global reservation)
//   K4 center GEMM: feat tile staged in LDS (coalesced, stride-68 pad), thread =
//      4 rows x 8 ch register block; W reads amortized 4x; conflict-free banks
//   K5 per-offset gather-GEMM: lane=channel, W in LDS, wave-per-4-pairs ILP,
//      coalesced 256B atomics. __launch_bounds__(256) lifts the default 64-VGPR
//      cap (R9/R10 lesson: default bounds assume 1024-thread blocks -> VGPR<=64
//      -> anything bigger silently spills to scratch: 0.9GB traffic, 8x slow).
//   K6 channel sum/sumsq reduction (padded atomics)
//   K7 normalize + leaky relu (in place on out)

#define DD 96
#define HH 320
#define WW 320
#define GRID_ELEMS (DD * HH * WW)
#define OCC_WORDS (GRID_ELEMS / 32)   // 1.2 MB; WW%32==0 => rows word-aligned
#define CIN 64
#define COUT 64
#define PAIR_CAP 16384
#define STAGE_CAP 40    // per-(block,k) staging; mean 3.9 hits, P(>40) ~ 0
#define TILE_R 128      // center_k rows per block
#define FSTRIDE 68      // LDS feat row stride (dwords): bank = 4g mod 32 -> conflict-free
#define EPSV 1e-5f
#define SLOPE 0.01f

__global__ void scatter_k(const int* __restrict__ coords, int* __restrict__ grid,
                          unsigned* __restrict__ occ, int N) {
    int i = blockIdx.x * 256 + threadIdx.x;
    if (i >= N) return;
    int z = coords[3 * i], y = coords[3 * i + 1], x = coords[3 * i + 2];
    int l = (z * HH + y) * WW + x;
    grid[l] = i;
    atomicOr(&occ[l >> 5], 1u << (l & 31));
}

// Per-voxel probe of L2-resident bitmask; hits staged in LDS; one padded global
// atomic per (block,k) reserves the compact range; bulk copy-out.
__global__ void rulebook_k(const int* __restrict__ coords, const int* __restrict__ grid,
                           const unsigned* __restrict__ occ,
                           int* __restrict__ cnt, int2* __restrict__ pairs, int N) {
    __shared__ int scnt[27];
    __shared__ int sbase[27];
    __shared__ int2 stage[27][STAGE_CAP];
    int tid = threadIdx.x;
    if (tid < 27) scnt[tid] = 0;
    __syncthreads();

    int i = blockIdx.x * 256 + tid;
    if (i < N) {
        int z = coords[3 * i], y = coords[3 * i + 1], x = coords[3 * i + 2];
        int lo = x > 0 ? x - 1 : 0;
        int hi = x < WW - 1 ? x + 1 : WW - 1;
        int wlo = lo >> 5, whi = hi >> 5;

        unsigned wa[9], wb9[9];
        int rwb[9];
#pragma unroll
        for (int r = 0; r < 9; ++r) {
            int zz = z + r / 3 - 1;
            int yy = y + r % 3 - 1;
            bool ok = ((unsigned)zz < DD) && ((unsigned)yy < HH);
            int base = (zz * HH + yy) * WW;      // word-aligned (WW % 32 == 0)
            rwb[r] = base;
            int wbase = base >> 5;
            wa[r]  = ok ? occ[wbase + wlo] : 0u;
            wb9[r] = ok ? occ[wbase + whi] : 0u;
        }
#pragma unroll
        for (int r = 0; r < 9; ++r) {
            for (int xx = lo; xx <= hi; ++xx) {
                if (r == 4 && xx == x) continue;          // center handled by center_k
                unsigned w = ((xx >> 5) == wlo) ? wa[r] : wb9[r];
                if ((w >> (xx & 31)) & 1u) {
                    int j = grid[rwb[r] + xx];
                    int k = r * 3 + (xx - x + 1);         // 0..26, never 13
                    int pos = atomicAdd(&scnt[k], 1);     // LDS atomic: cheap
                    if (pos < STAGE_CAP) stage[k][pos] = make_int2(i, j);
                }
            }
        }
    }
    __syncthreads();
    if (tid < 27) {
        int c = scnt[tid];
        if (c > STAGE_CAP) c = STAGE_CAP;
        scnt[tid] = c;
        if (c > 0) sbase[tid] = atomicAdd(&cnt[tid * 32], c);  // 128B-padded counters
    }
    __syncthreads();
    for (int s = tid; s < 27 * STAGE_CAP; s += 256) {
        int k = s / STAGE_CAP, p = s % STAGE_CAP;
        if (p < scnt[k]) {
            int pos = sbase[k] + p;
            if (pos < PAIR_CAP) pairs[k * PAIR_CAP + pos] = stage[k][p];
        }
    }
}

// Dense GEMM, 128-row tile in LDS. Thread = 4 rows (strided by 32) x 8 channels.
// Global reads/writes fully coalesced; LDS reads conflict-free (stride 68);
// W-fragment reads amortized over 4 rows in registers.
__global__ void __launch_bounds__(256) center_k(const float* __restrict__ feat,
                                                const float* __restrict__ w13,
                                                float* __restrict__ out, int N) {
    __shared__ float wl[CIN * COUT];          // 16 KB
    __shared__ float fl[TILE_R * FSTRIDE];    // 34.8 KB
    {
        const float4* ws4 = (const float4*)w13;
        float4* wl4 = (float4*)wl;
        for (int t = threadIdx.x; t < CIN * COUT / 4; t += 256) wl4[t] = ws4[t];
    }
    int base_row = blockIdx.x * TILE_R;
    for (int t = threadIdx.x; t < TILE_R * 16; t += 256) {
        int r = t >> 4, c4 = t & 15;
        int gr = base_row + r;
        float4 v = (gr < N) ? ((const float4*)feat)[(size_t)gr * 16 + c4]
                            : make_float4(0.f, 0.f, 0.f, 0.f);
        *(float4*)&fl[r * FSTRIDE + c4 * 4] = v;
    }
    __syncthreads();

    int g = threadIdx.x >> 3;            // 0..31: row within 32-row stripe
    int c0 = (threadIdx.x & 7) * 8;      // 8-channel group
    float4 acc[4][2];
#pragma unroll
    for (int r = 0; r < 4; ++r) {
        acc[r][0] = make_float4(0.f, 0.f, 0.f, 0.f);
        acc[r][1] = make_float4(0.f, 0.f, 0.f, 0.f);
    }
#pragma unroll 4
    for (int ci4 = 0; ci4 < 16; ++ci4) {
        float4 f[4];
#pragma unroll
        for (int r = 0; r < 4; ++r)
            f[r] = *(const float4*)&fl[(g + 32 * r) * FSTRIDE + ci4 * 4];
#pragma unroll
        for (int u = 0; u < 4; ++u) {
            float4 wa = *(const float4*)&wl[(ci4 * 4 + u) * COUT + c0];
            float4 wb = *(const float4*)&wl[(ci4 * 4 + u) * COUT + c0 + 4];
#pragma unroll
            for (int r = 0; r < 4; ++r) {
                float fv = (&f[r].x)[u];
                acc[r][0].x += fv * wa.x;
                acc[r][0].y += fv * wa.y;
                acc[r][0].z += fv * wa.z;
                acc[r][0].w += fv * wa.w;
                acc[r][1].x += fv * wb.x;
                acc[r][1].y += fv * wb.y;
                acc[r][1].z += fv * wb.z;
                acc[r][1].w += fv * wb.w;
            }
        }
    }
    float4* o4 = (float4*)out;
#pragma unroll
    for (int r = 0; r < 4; ++r) {
        int row = base_row + g + 32 * r;
        if (row < N) {
            size_t base = (size_t)row * 16 + (c0 >> 2);
            o4[base] = acc[r][0];
            o4[base + 1] = acc[r][1];
        }
    }
}

// Lane = output channel, W[k] staged in LDS. Wave-per-4-pairs: each wl scalar
// read feeds 4 accumulators; 4 broadcast load chains hide gather latency.
// atomicAdd per pair = ONE contiguous 256B region. launch_bounds(256) lifts
// the 64-VGPR default cap that was spilling this kernel to scratch.
__global__ void __launch_bounds__(256) offset_k(const float* __restrict__ feat,
                                                const float* __restrict__ weight,
                                                const int2* __restrict__ pairs,
                                                const int* __restrict__ cnt,
                                                float* __restrict__ out) {
    int k = blockIdx.y;
    if (k >= 13) ++k;  // skip center
    int ck = cnt[k * 32];
    if (ck > PAIR_CAP) ck = PAIR_CAP;
    if ((int)blockIdx.x * 16 >= ck) return;   // block-uniform early-out (before any sync)
    __shared__ float wl[CIN * COUT];
    {
        const float4* ws4 = (const float4*)(weight + (size_t)k * CIN * COUT);
        float4* wl4 = (float4*)wl;
        for (int t = threadIdx.x; t < CIN * COUT / 4; t += 256) wl4[t] = ws4[t];
    }
    __syncthreads();
    int wave = threadIdx.x >> 6;   // 0..3
    int lane = threadIdx.x & 63;   // output channel
    for (int p0 = (int)blockIdx.x * 16 + wave * 4; p0 < ck; p0 += (int)gridDim.x * 16) {
        int np = ck - p0;
        int2 pr0, pr1, pr2, pr3;
        pr0 = pairs[k * PAIR_CAP + p0];
        pr1 = pairs[k * PAIR_CAP + (1 < np ? p0 + 1 : p0)];
        pr2 = pairs[k * PAIR_CAP + (2 < np ? p0 + 2 : p0)];
        pr3 = pairs[k * PAIR_CAP + (3 < np ? p0 + 3 : p0)];
        const float4* fr0 = (const float4*)(feat + (size_t)pr0.y * CIN);
        const float4* fr1 = (const float4*)(feat + (size_t)pr1.y * CIN);
        const float4* fr2 = (const float4*)(feat + (size_t)pr2.y * CIN);
        const float4* fr3 = (const float4*)(feat + (size_t)pr3.y * CIN);
        float acc0 = 0.f, acc1 = 0.f, acc2 = 0.f, acc3 = 0.f;
#pragma unroll
        for (int ci4 = 0; ci4 < 16; ++ci4) {
            float4 f0 = fr0[ci4];                    // wave-uniform -> broadcast
            float4 f1 = fr1[ci4];
            float4 f2 = fr2[ci4];
            float4 f3 = fr3[ci4];
#pragma unroll
            for (int u = 0; u < 4; ++u) {
                float w = wl[(ci4 * 4 + u) * COUT + lane];
                acc0 += (&f0.x)[u] * w;
                acc1 += (&f1.x)[u] * w;
                acc2 += (&f2.x)[u] * w;
                acc3 += (&f3.x)[u] * w;
            }
        }
        atomicAdd(&out[(size_t)pr0.x * COUT + lane], acc0);
        if (1 < np) atomicAdd(&out[(size_t)pr1.x * COUT + lane], acc1);
        if (2 < np) atomicAdd(&out[(size_t)pr2.x * COUT + lane], acc2);
        if (3 < np) atomicAdd(&out[(size_t)pr3.x * COUT + lane], acc3);
    }
}

// Padded stats: stats[c*32] = sum_c, stats[(64+c)*32] = sumsq_c (128B per counter)
__global__ void stats_k(const float* __restrict__ out, float* __restrict__ stats, int N) {
    __shared__ float ssum[4][64];
    __shared__ float ssq[4][64];
    int c = threadIdx.x & 63, g = threadIdx.x >> 6;
    float s = 0.f, q = 0.f;
    for (int r = blockIdx.x * 4 + g; r < N; r += gridDim.x * 4) {
        float v = out[(size_t)r * 64 + c];
        s += v;
        q += v * v;
    }
    ssum[g][c] = s;
    ssq[g][c] = q;
    __syncthreads();
    if (threadIdx.x < 64) {
        float ts = ssum[0][c] + ssum[1][c] + ssum[2][c] + ssum[3][c];
        float tq = ssq[0][c] + ssq[1][c] + ssq[2][c] + ssq[3][c];
        atomicAdd(&stats[c * 32], ts);
        atomicAdd(&stats[(64 + c) * 32], tq);
    }
}

__global__ void norm_k(float* __restrict__ out, const float* __restrict__ stats,
                       const float* __restrict__ gamma, const float* __restrict__ beta, int N) {
    int idx = (int)blockIdx.x * 256 + threadIdx.x;
    int total = N * (COUT / 4);
    if (idx >= total) return;
    int c0 = (idx & 15) * 4;
    float inv = 1.0f / (float)N;
    float4 v = ((const float4*)out)[idx];
    float4 r;
#pragma unroll
    for (int u = 0; u < 4; ++u) {
        int c = c0 + u;
        float mean = stats[c * 32] * inv;
        float var = stats[(64 + c) * 32] * inv - mean * mean;
        if (var < 0.f) var = 0.f;
        float sc = gamma[c] * rsqrtf(var + EPSV);
        float sh = beta[c] - mean * sc;
        float y = (&v.x)[u] * sc + sh;
        (&r.x)[u] = (y >= 0.f) ? y : SLOPE * y;
    }
    ((float4*)out)[idx] = r;
}

extern "C" void kernel_launch(void* const* d_in, const int* in_sizes, int n_in,
                              void* d_out, int out_size, void* d_ws, size_t ws_size,
                              hipStream_t stream) {
    const float* feat   = (const float*)d_in[0];
    const int*   coords = (const int*)d_in[1];
    const float* weight = (const float*)d_in[2];
    const float* gamma  = (const float*)d_in[3];
    const float* beta   = (const float*)d_in[4];
    float* out = (float*)d_out;
    int N = in_sizes[0] / CIN;

    // workspace layout (~44.1 MB of the 256 MiB ws)
    char* ws = (char*)d_ws;
    int* grid = (int*)ws;                                   // 39.32 MB (gated by occ, no memset)
    size_t off = (size_t)GRID_ELEMS * 4;
    int* cnt = (int*)(ws + off);                            // 27*32 ints padded -> 4KB slot
    float* stats = (float*)(ws + off + 4096);               // 128*32 floats padded = 16KB
    int2* pairs = (int2*)(ws + off + 4096 + 16384);         // 27*PAIR_CAP*8 = 3.54 MB
    size_t occ_off = off + 4096 + 16384 + (size_t)27 * PAIR_CAP * 8;
    unsigned* occ = (unsigned*)(ws + occ_off);              // 1.2 MB bitmask

    hipMemsetAsync(ws + off, 0, 4096 + 16384, stream);      // counters + stats
    hipMemsetAsync(occ, 0, (size_t)OCC_WORDS * 4, stream);  // bitmask = 0

    int nb = (N + 255) / 256;
    scatter_k<<<nb, 256, 0, stream>>>(coords, grid, occ, N);
    rulebook_k<<<nb, 256, 0, stream>>>(coords, grid, occ, cnt, pairs, N);
    int nbc = (N + TILE_R - 1) / TILE_R;
    center_k<<<nbc, 256, 0, stream>>>(feat, weight + 13 * CIN * COUT, out, N);
    offset_k<<<dim3(96, 26), 256, 0, stream>>>(feat, weight, pairs, cnt, out);
    stats_k<<<256, 256, 0, stream>>>(out, stats, N);
    int nb4 = (N * (COUT / 4) + 255) / 256;
    norm_k<<<nb4, 256, 0, stream>>>(out, stats, gamma, beta, N);
}

// Round 12
// 275.889 us; speedup vs baseline: 1.9994x; 1.0949x over previous
//
#include <hip/hip_runtime.h>

// Sparse submanifold 3x3x3 conv (64->64) + BatchNorm(batch stats) + LeakyReLU(0.01)
// Rulebook strategy, occupancy bitmask, contention-free counters.
//   K1 memset cnt/stats (20KB) + occ bitmask (1.2MB)
//   K2 scatter: grid[lin]=i, atomicOr occ bit
//   K3 rulebook (block-aggregated LDS staging, padded global reservation)
//   K4 center GEMM: feat tile staged in LDS (coalesced, stride-68 pad), thread =
//      4 rows x 8 ch register block; W reads amortized 4x; conflict-free banks
//   K5 per-offset gather-GEMM: lane=channel, W in LDS, wave-per-2-pairs,
//      grid sized so ALL waves co-resident (one staging generation).
//      R9/R10 lesson: default launch bounds cap VGPR at 64 -> silent scratch
//      spill. R11 lesson: 4-pair ILP costs VGPR 136 -> 3 waves/SIMD -> 9.7%
//      occupancy, WORSE than 2-pair at 8 waves/SIMD. ILP trades 1:1 vs TLP
//      through the VGPR budget; favor TLP here (latency-bound gathers).
//   K6 channel sum/sumsq reduction (padded atomics)
//   K7 normalize + leaky relu (in place on out)

#define DD 96
#define HH 320
#define WW 320
#define GRID_ELEMS (DD * HH * WW)
#define OCC_WORDS (GRID_ELEMS / 32)   // 1.2 MB; WW%32==0 => rows word-aligned
#define CIN 64
#define COUT 64
#define PAIR_CAP 16384
#define STAGE_CAP 40    // per-(block,k) staging; mean 3.9 hits, P(>40) ~ 0
#define TILE_R 128      // center_k rows per block
#define FSTRIDE 68      // LDS feat row stride (dwords): bank = 4g mod 32 -> conflict-free
#define EPSV 1e-5f
#define SLOPE 0.01f

__global__ void scatter_k(const int* __restrict__ coords, int* __restrict__ grid,
                          unsigned* __restrict__ occ, int N) {
    int i = blockIdx.x * 256 + threadIdx.x;
    if (i >= N) return;
    int z = coords[3 * i], y = coords[3 * i + 1], x = coords[3 * i + 2];
    int l = (z * HH + y) * WW + x;
    grid[l] = i;
    atomicOr(&occ[l >> 5], 1u << (l & 31));
}

// Per-voxel probe of L2-resident bitmask; hits staged in LDS; one padded global
// atomic per (block,k) reserves the compact range; bulk copy-out.
__global__ void rulebook_k(const int* __restrict__ coords, const int* __restrict__ grid,
                           const unsigned* __restrict__ occ,
                           int* __restrict__ cnt, int2* __restrict__ pairs, int N) {
    __shared__ int scnt[27];
    __shared__ int sbase[27];
    __shared__ int2 stage[27][STAGE_CAP];
    int tid = threadIdx.x;
    if (tid < 27) scnt[tid] = 0;
    __syncthreads();

    int i = blockIdx.x * 256 + tid;
    if (i < N) {
        int z = coords[3 * i], y = coords[3 * i + 1], x = coords[3 * i + 2];
        int lo = x > 0 ? x - 1 : 0;
        int hi = x < WW - 1 ? x + 1 : WW - 1;
        int wlo = lo >> 5, whi = hi >> 5;

        unsigned wa[9], wb9[9];
        int rwb[9];
#pragma unroll
        for (int r = 0; r < 9; ++r) {
            int zz = z + r / 3 - 1;
            int yy = y + r % 3 - 1;
            bool ok = ((unsigned)zz < DD) && ((unsigned)yy < HH);
            int base = (zz * HH + yy) * WW;      // word-aligned (WW % 32 == 0)
            rwb[r] = base;
            int wbase = base >> 5;
            wa[r]  = ok ? occ[wbase + wlo] : 0u;
            wb9[r] = ok ? occ[wbase + whi] : 0u;
        }
#pragma unroll
        for (int r = 0; r < 9; ++r) {
            for (int xx = lo; xx <= hi; ++xx) {
                if (r == 4 && xx == x) continue;          // center handled by center_k
                unsigned w = ((xx >> 5) == wlo) ? wa[r] : wb9[r];
                if ((w >> (xx & 31)) & 1u) {
                    int j = grid[rwb[r] + xx];
                    int k = r * 3 + (xx - x + 1);         // 0..26, never 13
                    int pos = atomicAdd(&scnt[k], 1);     // LDS atomic: cheap
                    if (pos < STAGE_CAP) stage[k][pos] = make_int2(i, j);
                }
            }
        }
    }
    __syncthreads();
    if (tid < 27) {
        int c = scnt[tid];
        if (c > STAGE_CAP) c = STAGE_CAP;
        scnt[tid] = c;
        if (c > 0) sbase[tid] = atomicAdd(&cnt[tid * 32], c);  // 128B-padded counters
    }
    __syncthreads();
    for (int s = tid; s < 27 * STAGE_CAP; s += 256) {
        int k = s / STAGE_CAP, p = s % STAGE_CAP;
        if (p < scnt[k]) {
            int pos = sbase[k] + p;
            if (pos < PAIR_CAP) pairs[k * PAIR_CAP + pos] = stage[k][p];
        }
    }
}

// Dense GEMM, 128-row tile in LDS. Thread = 4 rows (strided by 32) x 8 channels.
// Global reads/writes fully coalesced; LDS reads conflict-free (stride 68);
// W-fragment reads amortized over 4 rows in registers.
__global__ void __launch_bounds__(256) center_k(const float* __restrict__ feat,
                                                const float* __restrict__ w13,
                                                float* __restrict__ out, int N) {
    __shared__ float wl[CIN * COUT];          // 16 KB
    __shared__ float fl[TILE_R * FSTRIDE];    // 34.8 KB
    {
        const float4* ws4 = (const float4*)w13;
        float4* wl4 = (float4*)wl;
        for (int t = threadIdx.x; t < CIN * COUT / 4; t += 256) wl4[t] = ws4[t];
    }
    int base_row = blockIdx.x * TILE_R;
    for (int t = threadIdx.x; t < TILE_R * 16; t += 256) {
        int r = t >> 4, c4 = t & 15;
        int gr = base_row + r;
        float4 v = (gr < N) ? ((const float4*)feat)[(size_t)gr * 16 + c4]
                            : make_float4(0.f, 0.f, 0.f, 0.f);
        *(float4*)&fl[r * FSTRIDE + c4 * 4] = v;
    }
    __syncthreads();

    int g = threadIdx.x >> 3;            // 0..31: row within 32-row stripe
    int c0 = (threadIdx.x & 7) * 8;      // 8-channel group
    float4 acc[4][2];
#pragma unroll
    for (int r = 0; r < 4; ++r) {
        acc[r][0] = make_float4(0.f, 0.f, 0.f, 0.f);
        acc[r][1] = make_float4(0.f, 0.f, 0.f, 0.f);
    }
#pragma unroll 4
    for (int ci4 = 0; ci4 < 16; ++ci4) {
        float4 f[4];
#pragma unroll
        for (int r = 0; r < 4; ++r)
            f[r] = *(const float4*)&fl[(g + 32 * r) * FSTRIDE + ci4 * 4];
#pragma unroll
        for (int u = 0; u < 4; ++u) {
            float4 wa = *(const float4*)&wl[(ci4 * 4 + u) * COUT + c0];
            float4 wb = *(const float4*)&wl[(ci4 * 4 + u) * COUT + c0 + 4];
#pragma unroll
            for (int r = 0; r < 4; ++r) {
                float fv = (&f[r].x)[u];
                acc[r][0].x += fv * wa.x;
                acc[r][0].y += fv * wa.y;
                acc[r][0].z += fv * wa.z;
                acc[r][0].w += fv * wa.w;
                acc[r][1].x += fv * wb.x;
                acc[r][1].y += fv * wb.y;
                acc[r][1].z += fv * wb.z;
                acc[r][1].w += fv * wb.w;
            }
        }
    }
    float4* o4 = (float4*)out;
#pragma unroll
    for (int r = 0; r < 4; ++r) {
        int row = base_row + g + 32 * r;
        if (row < N) {
            size_t base = (size_t)row * 16 + (c0 >> 2);
            o4[base] = acc[r][0];
            o4[base + 1] = acc[r][1];
        }
    }
}

// Lane = output channel, W[k] staged in LDS. Wave-per-2-PAIRS (VGPR ~56 ->
// 8 waves/SIMD); grid (64,26) puts all 6656 waves co-resident in ONE
// generation (6.5 blocks/CU x 16KB LDS fits), so W staging happens exactly
// once per block and each wave runs ~9 loop iterations.
__global__ void __launch_bounds__(256) offset_k(const float* __restrict__ feat,
                                                const float* __restrict__ weight,
                                                const int2* __restrict__ pairs,
                                                const int* __restrict__ cnt,
                                                float* __restrict__ out) {
    int k = blockIdx.y;
    if (k >= 13) ++k;  // skip center
    int ck = cnt[k * 32];
    if (ck > PAIR_CAP) ck = PAIR_CAP;
    if ((int)blockIdx.x * 8 >= ck) return;    // block-uniform early-out (before any sync)
    __shared__ float wl[CIN * COUT];
    {
        const float4* ws4 = (const float4*)(weight + (size_t)k * CIN * COUT);
        float4* wl4 = (float4*)wl;
        for (int t = threadIdx.x; t < CIN * COUT / 4; t += 256) wl4[t] = ws4[t];
    }
    __syncthreads();
    int wave = threadIdx.x >> 6;   // 0..3
    int lane = threadIdx.x & 63;   // output channel
    for (int p0 = (int)blockIdx.x * 8 + wave * 2; p0 < ck; p0 += (int)gridDim.x * 8) {
        bool hasB = (p0 + 1) < ck;
        int2 prA = pairs[k * PAIR_CAP + p0];
        int2 prB = pairs[k * PAIR_CAP + (hasB ? p0 + 1 : p0)];
        const float4* frA = (const float4*)(feat + (size_t)prA.y * CIN);
        const float4* frB = (const float4*)(feat + (size_t)prB.y * CIN);
        float accA = 0.f, accB = 0.f;
#pragma unroll
        for (int ci4 = 0; ci4 < 16; ++ci4) {
            float4 fa = frA[ci4];                    // wave-uniform -> broadcast
            float4 fb = frB[ci4];
#pragma unroll
            for (int u = 0; u < 4; ++u) {
                float w = wl[(ci4 * 4 + u) * COUT + lane];
                accA += (&fa.x)[u] * w;
                accB += (&fb.x)[u] * w;
            }
        }
        atomicAdd(&out[(size_t)prA.x * COUT + lane], accA);  // coalesced 256B region
        if (hasB) atomicAdd(&out[(size_t)prB.x * COUT + lane], accB);
    }
}

// Padded stats: stats[c*32] = sum_c, stats[(64+c)*32] = sumsq_c (128B per counter)
__global__ void stats_k(const float* __restrict__ out, float* __restrict__ stats, int N) {
    __shared__ float ssum[4][64];
    __shared__ float ssq[4][64];
    int c = threadIdx.x & 63, g = threadIdx.x >> 6;
    float s = 0.f, q = 0.f;
    for (int r = blockIdx.x * 4 + g; r < N; r += gridDim.x * 4) {
        float v = out[(size_t)r * 64 + c];
        s += v;
        q += v * v;
    }
    ssum[g][c] = s;
    ssq[g][c] = q;
    __syncthreads();
    if (threadIdx.x < 64) {
        float ts = ssum[0][c] + ssum[1][c] + ssum[2][c] + ssum[3][c];
        float tq = ssq[0][c] + ssq[1][c] + ssq[2][c] + ssq[3][c];
        atomicAdd(&stats[c * 32], ts);
        atomicAdd(&stats[(64 + c) * 32], tq);
    }
}

__global__ void norm_k(float* __restrict__ out, const float* __restrict__ stats,
                       const float* __restrict__ gamma, const float* __restrict__ beta, int N) {
    int idx = (int)blockIdx.x * 256 + threadIdx.x;
    int total = N * (COUT / 4);
    if (idx >= total) return;
    int c0 = (idx & 15) * 4;
    float inv = 1.0f / (float)N;
    float4 v = ((const float4*)out)[idx];
    float4 r;
#pragma unroll
    for (int u = 0; u < 4; ++u) {
        int c = c0 + u;
        float mean = stats[c * 32] * inv;
        float var = stats[(64 + c) * 32] * inv - mean * mean;
        if (var < 0.f) var = 0.f;
        float sc = gamma[c] * rsqrtf(var + EPSV);
        float sh = beta[c] - mean * sc;
        float y = (&v.x)[u] * sc + sh;
        (&r.x)[u] = (y >= 0.f) ? y : SLOPE * y;
    }
    ((float4*)out)[idx] = r;
}

extern "C" void kernel_launch(void* const* d_in, const int* in_sizes, int n_in,
                              void* d_out, int out_size, void* d_ws, size_t ws_size,
                              hipStream_t stream) {
    const float* feat   = (const float*)d_in[0];
    const int*   coords = (const int*)d_in[1];
    const float* weight = (const float*)d_in[2];
    const float* gamma  = (const float*)d_in[3];
    const float* beta   = (const float*)d_in[4];
    float* out = (float*)d_out;
    int N = in_sizes[0] / CIN;

    // workspace layout (~44.1 MB of the 256 MiB ws)
    char* ws = (char*)d_ws;
    int* grid = (int*)ws;                                   // 39.32 MB (gated by occ, no memset)
    size_t off = (size_t)GRID_ELEMS * 4;
    int* cnt = (int*)(ws + off);                            // 27*32 ints padded -> 4KB slot
    float* stats = (float*)(ws + off + 4096);               // 128*32 floats padded = 16KB
    int2* pairs = (int2*)(ws + off + 4096 + 16384);         // 27*PAIR_CAP*8 = 3.54 MB
    size_t occ_off = off + 4096 + 16384 + (size_t)27 * PAIR_CAP * 8;
    unsigned* occ = (unsigned*)(ws + occ_off);              // 1.2 MB bitmask

    hipMemsetAsync(ws + off, 0, 4096 + 16384, stream);      // counters + stats
    hipMemsetAsync(occ, 0, (size_t)OCC_WORDS * 4, stream);  // bitmask = 0

    int nb = (N + 255) / 256;
    scatter_k<<<nb, 256, 0, stream>>>(coords, grid, occ, N);
    rulebook_k<<<nb, 256, 0, stream>>>(coords, grid, occ, cnt, pairs, N);
    int nbc = (N + TILE_R - 1) / TILE_R;
    center_k<<<nbc, 256, 0, stream>>>(feat, weight + 13 * CIN * COUT, out, N);
    offset_k<<<dim3(64, 26), 256, 0, stream>>>(feat, weight, pairs, cnt, out);
    stats_k<<<256, 256, 0, stream>>>(out, stats, N);
    int nb4 = (N * (COUT / 4) + 255) / 256;
    norm_k<<<nb4, 256, 0, stream>>>(out, stats, gamma, beta, N);
}

// Round 13
// 258.413 us; speedup vs baseline: 2.1347x; 1.0676x over previous
//
#include <hip/hip_runtime.h>

// Sparse submanifold 3x3x3 conv (64->64) + BatchNorm(batch stats) + LeakyReLU(0.01)
// Rulebook strategy, occupancy bitmask, contention-free counters.
//   K1 single memset: cnt(4KB)+stats(16KB)+occ(1.2MB) contiguous
//   K2 scatter: grid[lin]=i, atomicOr occ bit
//   K3 rulebook (block-aggregated LDS staging, padded global reservation)
//   K4 center GEMM: feat tile in LDS (stride-68 pad), 4 rows x 8 ch per thread
//   K5 per-offset gather-GEMM: lane=channel, W^T in LDS with XOR swizzle so the
//      per-lane weight read is ONE ds_read_b128 (was 4x ds_read_b32 scalar
//      column reads). Swizzle phys = c*64 + ((ci4 ^ (c&7))<<2) gives perfectly
//      even bank spread (8 dwords/bank/wave-read = minimum).
//      R9/R10 lesson: default launch bounds cap VGPR at 64 -> silent spill.
//      R11 lesson: 4-pair ILP (VGPR 136, 3 waves/SIMD) loses to 2-pair TLP.
//   K6 channel sum/sumsq: float4 reads, 1024 blocks, padded atomics
//   K7 normalize + leaky relu (in place on out)

#define DD 96
#define HH 320
#define WW 320
#define GRID_ELEMS (DD * HH * WW)
#define OCC_WORDS (GRID_ELEMS / 32)   // 1.2 MB; WW%32==0 => rows word-aligned
#define CIN 64
#define COUT 64
#define PAIR_CAP 16384
#define STAGE_CAP 40    // per-(block,k) staging; mean 3.9 hits, P(>40) ~ 0
#define TILE_R 128      // center_k rows per block
#define FSTRIDE 68      // LDS feat row stride (dwords): bank = 4g mod 32 -> conflict-free
#define EPSV 1e-5f
#define SLOPE 0.01f

__global__ void scatter_k(const int* __restrict__ coords, int* __restrict__ grid,
                          unsigned* __restrict__ occ, int N) {
    int i = blockIdx.x * 256 + threadIdx.x;
    if (i >= N) return;
    int z = coords[3 * i], y = coords[3 * i + 1], x = coords[3 * i + 2];
    int l = (z * HH + y) * WW + x;
    grid[l] = i;
    atomicOr(&occ[l >> 5], 1u << (l & 31));
}

// Per-voxel probe of L2-resident bitmask; hits staged in LDS; one padded global
// atomic per (block,k) reserves the compact range; bulk copy-out.
__global__ void rulebook_k(const int* __restrict__ coords, const int* __restrict__ grid,
                           const unsigned* __restrict__ occ,
                           int* __restrict__ cnt, int2* __restrict__ pairs, int N) {
    __shared__ int scnt[27];
    __shared__ int sbase[27];
    __shared__ int2 stage[27][STAGE_CAP];
    int tid = threadIdx.x;
    if (tid < 27) scnt[tid] = 0;
    __syncthreads();

    int i = blockIdx.x * 256 + tid;
    if (i < N) {
        int z = coords[3 * i], y = coords[3 * i + 1], x = coords[3 * i + 2];
        int lo = x > 0 ? x - 1 : 0;
        int hi = x < WW - 1 ? x + 1 : WW - 1;
        int wlo = lo >> 5, whi = hi >> 5;

        unsigned wa[9], wb9[9];
        int rwb[9];
#pragma unroll
        for (int r = 0; r < 9; ++r) {
            int zz = z + r / 3 - 1;
            int yy = y + r % 3 - 1;
            bool ok = ((unsigned)zz < DD) && ((unsigned)yy < HH);
            int base = (zz * HH + yy) * WW;      // word-aligned (WW % 32 == 0)
            rwb[r] = base;
            int wbase = base >> 5;
            wa[r]  = ok ? occ[wbase + wlo] : 0u;
            wb9[r] = ok ? occ[wbase + whi] : 0u;
        }
#pragma unroll
        for (int r = 0; r < 9; ++r) {
            for (int xx = lo; xx <= hi; ++xx) {
                if (r == 4 && xx == x) continue;          // center handled by center_k
                unsigned w = ((xx >> 5) == wlo) ? wa[r] : wb9[r];
                if ((w >> (xx & 31)) & 1u) {
                    int j = grid[rwb[r] + xx];
                    int k = r * 3 + (xx - x + 1);         // 0..26, never 13
                    int pos = atomicAdd(&scnt[k], 1);     // LDS atomic: cheap
                    if (pos < STAGE_CAP) stage[k][pos] = make_int2(i, j);
                }
            }
        }
    }
    __syncthreads();
    if (tid < 27) {
        int c = scnt[tid];
        if (c > STAGE_CAP) c = STAGE_CAP;
        scnt[tid] = c;
        if (c > 0) sbase[tid] = atomicAdd(&cnt[tid * 32], c);  // 128B-padded counters
    }
    __syncthreads();
    for (int s = tid; s < 27 * STAGE_CAP; s += 256) {
        int k = s / STAGE_CAP, p = s % STAGE_CAP;
        if (p < scnt[k]) {
            int pos = sbase[k] + p;
            if (pos < PAIR_CAP) pairs[k * PAIR_CAP + pos] = stage[k][p];
        }
    }
}

// Dense GEMM, 128-row tile in LDS. Thread = 4 rows (strided by 32) x 8 channels.
// Global reads/writes fully coalesced; LDS reads conflict-free (stride 68);
// W-fragment reads amortized over 4 rows in registers.
__global__ void __launch_bounds__(256) center_k(const float* __restrict__ feat,
                                                const float* __restrict__ w13,
                                                float* __restrict__ out, int N) {
    __shared__ float wl[CIN * COUT];          // 16 KB
    __shared__ float fl[TILE_R * FSTRIDE];    // 34.8 KB
    {
        const float4* ws4 = (const float4*)w13;
        float4* wl4 = (float4*)wl;
        for (int t = threadIdx.x; t < CIN * COUT / 4; t += 256) wl4[t] = ws4[t];
    }
    int base_row = blockIdx.x * TILE_R;
    for (int t = threadIdx.x; t < TILE_R * 16; t += 256) {
        int r = t >> 4, c4 = t & 15;
        int gr = base_row + r;
        float4 v = (gr < N) ? ((const float4*)feat)[(size_t)gr * 16 + c4]
                            : make_float4(0.f, 0.f, 0.f, 0.f);
        *(float4*)&fl[r * FSTRIDE + c4 * 4] = v;
    }
    __syncthreads();

    int g = threadIdx.x >> 3;            // 0..31: row within 32-row stripe
    int c0 = (threadIdx.x & 7) * 8;      // 8-channel group
    float4 acc[4][2];
#pragma unroll
    for (int r = 0; r < 4; ++r) {
        acc[r][0] = make_float4(0.f, 0.f, 0.f, 0.f);
        acc[r][1] = make_float4(0.f, 0.f, 0.f, 0.f);
    }
#pragma unroll 4
    for (int ci4 = 0; ci4 < 16; ++ci4) {
        float4 f[4];
#pragma unroll
        for (int r = 0; r < 4; ++r)
            f[r] = *(const float4*)&fl[(g + 32 * r) * FSTRIDE + ci4 * 4];
#pragma unroll
        for (int u = 0; u < 4; ++u) {
            float4 wa = *(const float4*)&wl[(ci4 * 4 + u) * COUT + c0];
            float4 wb = *(const float4*)&wl[(ci4 * 4 + u) * COUT + c0 + 4];
#pragma unroll
            for (int r = 0; r < 4; ++r) {
                float fv = (&f[r].x)[u];
                acc[r][0].x += fv * wa.x;
                acc[r][0].y += fv * wa.y;
                acc[r][0].z += fv * wa.z;
                acc[r][0].w += fv * wa.w;
                acc[r][1].x += fv * wb.x;
                acc[r][1].y += fv * wb.y;
                acc[r][1].z += fv * wb.z;
                acc[r][1].w += fv * wb.w;
            }
        }
    }
    float4* o4 = (float4*)out;
#pragma unroll
    for (int r = 0; r < 4; ++r) {
        int row = base_row + g + 32 * r;
        if (row < N) {
            size_t base = (size_t)row * 16 + (c0 >> 2);
            o4[base] = acc[r][0];
            o4[base + 1] = acc[r][1];
        }
    }
}

// Lane = output channel. W^T staged in LDS with XOR swizzle: phys dword =
// c*64 + ((ci4 ^ (c&7))<<2). Lane's 4 weights = ONE ds_read_b128, banks
// perfectly spread (8 dwords/bank/wave-read). Wave-per-2-pairs, grid 96x26.
__global__ void __launch_bounds__(256) offset_k(const float* __restrict__ feat,
                                                const float* __restrict__ weight,
                                                const int2* __restrict__ pairs,
                                                const int* __restrict__ cnt,
                                                float* __restrict__ out) {
    int k = blockIdx.y;
    if (k >= 13) ++k;  // skip center
    int ck = cnt[k * 32];
    if (ck > PAIR_CAP) ck = PAIR_CAP;
    if ((int)blockIdx.x * 8 >= ck) return;    // block-uniform early-out (before any sync)
    __shared__ float wlT[CIN * COUT];
    {
        int c = threadIdx.x & 63;
        int q4 = threadIdx.x >> 6;            // 0..3
        const float* wk = weight + (size_t)k * CIN * COUT;
        int sw = c & 7;
#pragma unroll
        for (int r = 0; r < 4; ++r) {
            int ci4 = q4 * 4 + r;             // 0..15
            float4 v;
            v.x = wk[(ci4 * 4 + 0) * COUT + c];   // coalesced across c
            v.y = wk[(ci4 * 4 + 1) * COUT + c];
            v.z = wk[(ci4 * 4 + 2) * COUT + c];
            v.w = wk[(ci4 * 4 + 3) * COUT + c];
            *(float4*)&wlT[(c << 6) + ((ci4 ^ sw) << 2)] = v;
        }
    }
    __syncthreads();
    int wave = threadIdx.x >> 6;   // 0..3
    int lane = threadIdx.x & 63;   // output channel
    int sw = lane & 7;
    for (int p0 = (int)blockIdx.x * 8 + wave * 2; p0 < ck; p0 += (int)gridDim.x * 8) {
        bool hasB = (p0 + 1) < ck;
        int2 prA = pairs[k * PAIR_CAP + p0];
        int2 prB = pairs[k * PAIR_CAP + (hasB ? p0 + 1 : p0)];
        const float4* frA = (const float4*)(feat + (size_t)prA.y * CIN);
        const float4* frB = (const float4*)(feat + (size_t)prB.y * CIN);
        float accA = 0.f, accB = 0.f;
#pragma unroll
        for (int ci4 = 0; ci4 < 16; ++ci4) {
            float4 w = *(const float4*)&wlT[(lane << 6) + ((ci4 ^ sw) << 2)];  // b128
            float4 fa = frA[ci4];                    // wave-uniform -> broadcast
            float4 fb = frB[ci4];
            accA += fa.x * w.x + fa.y * w.y + fa.z * w.z + fa.w * w.w;
            accB += fb.x * w.x + fb.y * w.y + fb.z * w.z + fb.w * w.w;
        }
        atomicAdd(&out[(size_t)prA.x * COUT + lane], accA);  // coalesced 256B region
        if (hasB) atomicAdd(&out[(size_t)prB.x * COUT + lane], accB);
    }
}

// float4-vectorized stats: thread = (row-group g, channel-quad c4); 1024 blocks.
// Padded atomics: stats[c*32] = sum_c, stats[(64+c)*32] = sumsq_c.
__global__ void stats_k(const float* __restrict__ out, float* __restrict__ stats, int N) {
    __shared__ float ssum[16][64];
    __shared__ float ssq[16][64];
    int c4 = threadIdx.x & 15;       // channel quad
    int g = threadIdx.x >> 4;        // 0..15 row group
    float s0 = 0.f, s1 = 0.f, s2 = 0.f, s3 = 0.f;
    float q0 = 0.f, q1 = 0.f, q2 = 0.f, q3 = 0.f;
    for (int r = blockIdx.x * 16 + g; r < N; r += gridDim.x * 16) {
        float4 v = ((const float4*)out)[(size_t)r * 16 + c4];
        s0 += v.x; q0 += v.x * v.x;
        s1 += v.y; q1 += v.y * v.y;
        s2 += v.z; q2 += v.z * v.z;
        s3 += v.w; q3 += v.w * v.w;
    }
    ssum[g][c4 * 4 + 0] = s0; ssq[g][c4 * 4 + 0] = q0;
    ssum[g][c4 * 4 + 1] = s1; ssq[g][c4 * 4 + 1] = q1;
    ssum[g][c4 * 4 + 2] = s2; ssq[g][c4 * 4 + 2] = q2;
    ssum[g][c4 * 4 + 3] = s3; ssq[g][c4 * 4 + 3] = q3;
    __syncthreads();
    if (threadIdx.x < 64) {
        float ts = 0.f, tq = 0.f;
#pragma unroll
        for (int gg = 0; gg < 16; ++gg) {
            ts += ssum[gg][threadIdx.x];
            tq += ssq[gg][threadIdx.x];
        }
        atomicAdd(&stats[threadIdx.x * 32], ts);
        atomicAdd(&stats[(64 + threadIdx.x) * 32], tq);
    }
}

__global__ void norm_k(float* __restrict__ out, const float* __restrict__ stats,
                       const float* __restrict__ gamma, const float* __restrict__ beta, int N) {
    int idx = (int)blockIdx.x * 256 + threadIdx.x;
    int total = N * (COUT / 4);
    if (idx >= total) return;
    int c0 = (idx & 15) * 4;
    float inv = 1.0f / (float)N;
    float4 v = ((const float4*)out)[idx];
    float4 r;
#pragma unroll
    for (int u = 0; u < 4; ++u) {
        int c = c0 + u;
        float mean = stats[c * 32] * inv;
        float var = stats[(64 + c) * 32] * inv - mean * mean;
        if (var < 0.f) var = 0.f;
        float sc = gamma[c] * rsqrtf(var + EPSV);
        float sh = beta[c] - mean * sc;
        float y = (&v.x)[u] * sc + sh;
        (&r.x)[u] = (y >= 0.f) ? y : SLOPE * y;
    }
    ((float4*)out)[idx] = r;
}

extern "C" void kernel_launch(void* const* d_in, const int* in_sizes, int n_in,
                              void* d_out, int out_size, void* d_ws, size_t ws_size,
                              hipStream_t stream) {
    const float* feat   = (const float*)d_in[0];
    const int*   coords = (const int*)d_in[1];
    const float* weight = (const float*)d_in[2];
    const float* gamma  = (const float*)d_in[3];
    const float* beta   = (const float*)d_in[4];
    float* out = (float*)d_out;
    int N = in_sizes[0] / CIN;

    // workspace layout (~44.1 MB of the 256 MiB ws); cnt|stats|occ contiguous
    char* ws = (char*)d_ws;
    int* grid = (int*)ws;                                   // 39.32 MB (gated by occ, no memset)
    size_t off = (size_t)GRID_ELEMS * 4;
    int* cnt = (int*)(ws + off);                            // 4 KB (27 counters, 128B-padded)
    float* stats = (float*)(ws + off + 4096);               // 16 KB (128 padded counters)
    unsigned* occ = (unsigned*)(ws + off + 4096 + 16384);   // 1.2 MB bitmask
    int2* pairs = (int2*)(ws + off + 4096 + 16384 + (size_t)OCC_WORDS * 4);  // 3.54 MB

    hipMemsetAsync(ws + off, 0, 4096 + 16384 + (size_t)OCC_WORDS * 4, stream);  // one memset

    int nb = (N + 255) / 256;
    scatter_k<<<nb, 256, 0, stream>>>(coords, grid, occ, N);
    rulebook_k<<<nb, 256, 0, stream>>>(coords, grid, occ, cnt, pairs, N);
    int nbc = (N + TILE_R - 1) / TILE_R;
    center_k<<<nbc, 256, 0, stream>>>(feat, weight + 13 * CIN * COUT, out, N);
    offset_k<<<dim3(96, 26), 256, 0, stream>>>(feat, weight, pairs, cnt, out);
    stats_k<<<1024, 256, 0, stream>>>(out, stats, N);
    int nb4 = (N * (COUT / 4) + 255) / 256;
    norm_k<<<nb4, 256, 0, stream>>>(out, stats, gamma, beta, N);
}